// Round 9
// baseline (242.862 us; speedup 1.0000x reference)
//
#include <hip/hip_runtime.h>

// CRF forward partition, MI355X. B=1024, L=512, T=52.
//
// R15 = R14 resubmit (round 8 failed on container acquisition, no kernel
// evidence) with a __has_builtin guard on update_dpp as compile hardening.
//
// R14: register-resident reduce-scatter matvec — NO LDS in the main loop.
// Evidence R6-R13: wall/step = core(~630) + sum of waves' issue; core is the
// LDS write->read round trip (~400cyc). Fix: distribute-then-reduce.
//  - lane j owns tag tau(j) = j ^ ((j&4)?11:0)  (GF2-linear bijection;
//    tau(0)=0; maps lanes 0..51 onto tags 0..51, pads stay pads)
//  - products: P[r] = x * C[r], 64 cols padded, col(r) = rho(r) ^ tau(j)
//    (lane-relative layout), 32 v_pk_mul_f32
//  - 6-stage xor reduce-scatter, masks {1,2,8,15,16,32} (GF2-independent;
//    tau(m) = {1,2,8,4,16,32} = rho's column deltas, stage identity
//    rho(r+half)^tau(i^m) == rho(r)^tau(i) verified by induction):
//    xor1 = DPP quad_perm[1,0,3,2], xor2 = quad_perm[2,3,0,1],
//    xor8 = row_ror:8, xor15 = row_mirror (all DPP adds, VALU latency),
//    xor16 = shfl_xor, xor32 = permlane32_swap (HW-verified R11/R12)
//  - lane j ends with column tau(j) = its own next state. Chain latency
//    ~80cyc vs 630. Issue ~210/wave-step.
//   fwd:  p'[c] = ef[c] * sum_i E[i][c] p[i]       (t = 1..256)
//   bwd:  w'[c] = sum_i E[c][i] (ef[i] w[i])       (t = 511..257)
//   out:  log(sum_c u[c]*w[c]) + shiftF + shiftB   (masked step = identity)

#define TT 52       // TAG_SIZE
#define LL 512      // sequence length
#define NS 8        // steps per group; normalize once per group

typedef float v2f __attribute__((ext_vector_type(2)));
typedef unsigned int uv2 __attribute__((ext_vector_type(2)));

__device__ __forceinline__ float rl(float x, int lane) {
    return __int_as_float(__builtin_amdgcn_readlane(__float_as_int(x), lane));
}

// Cross-lane fetch of v[lane ^ m] for m in {1,2,8,15}: DPP when available.
template <int CTRL, int M>
__device__ __forceinline__ float dppx(float v) {
#if __has_builtin(__builtin_amdgcn_update_dpp)
    return __int_as_float(__builtin_amdgcn_update_dpp(
        0, __float_as_int(v), CTRL, 0xF, 0xF, true));
#else
    return __shfl_xor(v, M, 64);
#endif
}

// xor32 exchange via permlane32_swap (verified R11/R12):
// self-swap: r.x = [v.lo|v.lo], r.y = [v.hi|v.hi]; half-select = v[lane^32].
__device__ __forceinline__ float xhalf(float v, bool hlo) {
#if __has_builtin(__builtin_amdgcn_permlane32_swap)
    uv2 r = __builtin_amdgcn_permlane32_swap(__float_as_uint(v),
                                             __float_as_uint(v), false, false);
    return hlo ? __uint_as_float(r.y) : __uint_as_float(r.x);
#else
    return __shfl_xor(v, 32, 64);
#endif
}

// Register layout bit-shuffle: register bits (5..0) -> column deltas
// (1,2,8,4,16,32), matching stage masks {1,2,8,15,16,32} via tau.
constexpr int rho(int r) {
    return ((r >> 5) & 1) | (((r >> 4) & 1) << 1) | (((r >> 3) & 1) << 3) |
           (((r >> 2) & 1) << 2) | (((r >> 1) & 1) << 4) | ((r & 1) << 5);
}

// Reduce-scatter matvec: x = this lane's state entry; C2[k] packs coefficients
// for columns rho(2k)^tau, rho(2k+1)^tau. Returns s[tau(lane)] = full column
// dot for this lane's own tag.
__device__ __forceinline__ float rsmv(float x, const v2f* C2, bool hlo) {
    float P[64];
#pragma unroll
    for (int k = 0; k < 32; ++k) {
        v2f xx; xx.x = x; xx.y = x;
        v2f pr = xx * C2[k];
        P[2 * k] = pr.x; P[2 * k + 1] = pr.y;
    }
#pragma unroll
    for (int r = 0; r < 32; ++r) P[r] += dppx<0xB1, 1>(P[r + 32]);   // xor1
#pragma unroll
    for (int r = 0; r < 16; ++r) P[r] += dppx<0x4E, 2>(P[r + 16]);   // xor2
#pragma unroll
    for (int r = 0; r < 8; ++r)  P[r] += dppx<0x128, 8>(P[r + 8]);   // xor8
#pragma unroll
    for (int r = 0; r < 4; ++r)  P[r] += dppx<0x140, 15>(P[r + 4]);  // xor15
#pragma unroll
    for (int r = 0; r < 2; ++r)  P[r] += __shfl_xor(P[r + 2], 16, 64); // xor16
    P[0] += xhalf(P[1], hlo);                                        // xor32
    return P[0];
}

__global__ void __launch_bounds__(128)
__attribute__((amdgpu_waves_per_eu(2, 2)))
crf_fwd(
    const float* __restrict__ feats,   // (B, L, T)
    const int*   __restrict__ mask,    // (B, L)
    const float* __restrict__ trans,   // (T, T)
    float*       __restrict__ out)     // scalar accumulator (pre-zeroed)
{
    __shared__ float plds[2][64];      // final combine only (not in loop)
    __shared__ float shsh[2];

    const int b   = blockIdx.x;
    const int tid = threadIdx.x;
    const int w   = tid >> 6;           // 0 = fwd wave, 1 = bwd wave
    const int j   = tid & 63;
    const bool hlo = (j < 32);
    const int tau = (j & 4) ? (j ^ 11) : j;   // this lane's tag
    const bool act = (j < TT);          // tau bijects {0..51}<->{0..51}
    const int tc = act ? tau : 0;       // clamped tag for safe loads

    const float* fb = feats + (size_t)b * LL * TT;
    const int*   mb = mask  + (size_t)b * LL;

    float pv;      // this wave's state entry: p[tau] (fwd) / w[tau] (bwd)
    float shift;   // log of accumulated normalization factors

    // Coefficient pack: C2[k] for columns c = rho(2k)^tau, rho(2k+1)^tau.
    //  fwd: coef = E[tau][c] = exp(trans[tau*TT + c])   (source tau -> col c)
    //  bwd: coef = E[c][tau] = exp(trans[c*TT + tau])
    v2f C2[32];
#pragma unroll
    for (int k = 0; k < 32; ++k) {
        int c0 = rho(2 * k) ^ tau;
        int c1 = rho(2 * k + 1) ^ tau;
        int c0c = c0 < TT ? c0 : 0;
        int c1c = c1 < TT ? c1 : 0;
        float e0, e1;
        if (w == 0) {
            e0 = __expf(trans[tc * TT + c0c]);
            e1 = __expf(trans[tc * TT + c1c]);
        } else {
            e0 = __expf(trans[c0c * TT + tc]);
            e1 = __expf(trans[c1c * TT + tc]);
        }
        C2[k].x = (act && c0 < TT) ? e0 : 0.0f;
        C2[k].y = (act && c1 < TT) ? e1 : 0.0f;
    }

    if (w == 0) {
        // ---------------- forward chain: t = 1 .. 256 ----------------
        float part0 = act ? (fb[tau] + trans[(TT - 2) * TT + tau]) : -1.0e30f;
        shift = rl(part0, 0);               // lane 0 = tag 0 (tau(0)=0)
        pv = act ? __expf(part0 - shift) : 0.0f;

        float fA[NS], fB[NS]; int mA[NS], mB[NS];
#pragma unroll
        for (int u = 0; u < NS; ++u) {
            fA[u] = fb[(1 + u) * TT + tc];
            mA[u] = mb[1 + u];
        }

        auto fwd_group = [&](float (&fp)[NS], int (&mc)[NS],
                             float (&fn)[NS], int (&mn)[NS], int t0) {
#pragma unroll
            for (int u = 0; u < NS; ++u) {
                int tn = t0 + NS + u;            // <= 264 < LL, in-bounds
                fn[u] = fb[tn * TT + tc];
                mn[u] = mb[tn];
            }
            float ef[NS];
#pragma unroll
            for (int u = 0; u < NS; ++u) ef[u] = __expf(fp[u]);
#pragma unroll
            for (int u = 0; u < NS; ++u) {
                float pn = rsmv(pv, C2, hlo) * ef[u];
                pv = (mc[u] > 0) ? pn : pv;      // branchless mask select
                if (u == NS - 1) {
                    float c = rl(pv, 0);
                    shift += __logf(c);
                    pv *= __builtin_amdgcn_rcpf(c);
                }
            }
        };

        // 32 groups (t0 = 1..249) as 16 ping-pong pairs: t = 1..256 exactly.
        for (int t0 = 1; t0 <= 241; t0 += 2 * NS) {
            fwd_group(fA, mA, fB, mB, t0);
            fwd_group(fB, mB, fA, mA, t0 + NS);
        }
    } else {
        // ---------------- backward chain: t = 511 .. 257 ----------------
        pv = act ? __expf(trans[tc * TT + (TT - 1)]) : 0.0f;  // w = E[:,END]
        shift = 0.0f;

        float fA[NS], fB[NS]; int mA[NS], mB[NS];
#pragma unroll
        for (int u = 0; u < NS; ++u) {
            fA[u] = fb[(LL - 1 - u) * TT + tc];
            mA[u] = mb[LL - 1 - u];
        }

        auto bwd_group = [&](float (&fp)[NS], int (&mc)[NS],
                             float (&fn)[NS], int (&mn)[NS], int g) {
#pragma unroll
            for (int u = 0; u < NS; ++u) {
                int kn = g + NS + u;             // <= 255 -> t >= 256, in-bounds
                fn[u] = fb[(LL - 1 - kn) * TT + tc];
                mn[u] = mb[LL - 1 - kn];
            }
            float ef[NS];
#pragma unroll
            for (int u = 0; u < NS; ++u) ef[u] = __expf(fp[u]);
#pragma unroll
            for (int u = 0; u < NS; ++u) {
                float pn = rsmv(ef[u] * pv, C2, hlo);
                pv = (mc[u] > 0) ? pn : pv;      // branchless mask select
                if (u == NS - 1) {
                    float c = rl(pv, 0);
                    shift += __logf(c);
                    pv *= __builtin_amdgcn_rcpf(c);
                }
            }
        };

        // 30 groups as 15 ping-pong pairs (k = 0..239), 1 single group
        // (k = 240..247, prefetches k = 248..255 into fB), then 7-step tail.
        for (int g = 0; g <= 224; g += 2 * NS) {
            bwd_group(fA, mA, fB, mB, g);
            bwd_group(fB, mB, fA, mA, g + NS);
        }
        bwd_group(fA, mA, fB, mB, 240);

        // Tail: 7 steps, k = 248..254 (data in fB[0..6]).
#pragma unroll
        for (int u = 0; u < 7; ++u) {
            float pn = rsmv(__expf(fB[u]) * pv, C2, hlo);
            pv = (mB[u] > 0) ? pn : pv;
        }

        // Final safety normalize (bounds w away from inf before combine).
        {
            float c = rl(pv, 0);
            shift += __logf(c);
            pv *= __builtin_amdgcn_rcpf(c);
        }
    }

    // ------- combine: S = log(sum_c u[c]*w[c]) + shiftF + shiftB -------
    // Lane j of both waves holds tag tau(j) -> aligned products.
    plds[w][j] = pv;
    if (j == 0) shsh[w] = shift;
    __syncthreads();

    if (w == 0) {
        float wj  = plds[1][j];                  // bwd value, same tag
        float val = act ? (pv * wj) : 0.0f;
#pragma unroll
        for (int o = 32; o >= 1; o >>= 1)
            val += __shfl_xor(val, o, 64);
        if (j == 0) atomicAdd(out, __logf(val) + shift + shsh[1]);
    }
}

extern "C" void kernel_launch(void* const* d_in, const int* in_sizes, int n_in,
                              void* d_out, int out_size, void* d_ws, size_t ws_size,
                              hipStream_t stream) {
    const float* feats = (const float*)d_in[0];
    const int*   mask  = (const int*)d_in[1];
    const float* trans = (const float*)d_in[2];
    float* out = (float*)d_out;

    const int B = in_sizes[1] / LL;   // mask is (B, L)

    hipMemsetAsync(d_out, 0, sizeof(float), stream);
    crf_fwd<<<B, 128, 0, stream>>>(feats, mask, trans, out);
}